// Round 4
// baseline (87.405 us; speedup 1.0000x reference)
//
#include <hip/hip_runtime.h>

// Additive RQ kernel, symmetric: covar[i,j] = os * sum_d (1 + ((x_i,d-x_j,d)/l_d)^2/(2a))^(-a)
// Output layout: [ mean (N floats, zeros) | covar (N*N floats) ]
// Upper-triangle 32x32 tiles; mirror via LDS transpose.
// pow() replaced by piecewise-linear LDS table indexed by float bits of t=1+z:
//   idx = (bits>>17)-8128  (exponent + 6 mantissa bits, t in [1,4096))
//   frac = bits & 0x1FFFF; term = f0tab[idx] + frac*dtab[idx]
// Interp error <= alpha(alpha+1)/32768 ~ 1.8e-4/term, x32 terms = 0.006 << 0.577 threshold.

#define D 32
#define TILE 32
#define TAB_N 768          // 12 octaves x 64 buckets: t in [1, 4096)
#define TAB_BASE 8128      // 0x3f800000 >> 17

#if __has_builtin(__builtin_amdgcn_exp2f)
#define EXP2F(x) __builtin_amdgcn_exp2f(x)
#else
#define EXP2F(x) exp2f(x)
#endif
#if __has_builtin(__builtin_amdgcn_logf)
#define LOG2F(x) __builtin_amdgcn_logf(x)
#else
#define LOG2F(x) __log2f(x)
#endif

__global__ __launch_bounds__(256) void rq_covar_sym_kernel(
    const float* __restrict__ x,
    const float* __restrict__ ls,
    const float* __restrict__ alpha_p,
    const float* __restrict__ os_p,
    float* __restrict__ mean_out,
    float* __restrict__ covar,
    int n, int ntiles)
{
    __shared__ float As[TILE][36];
    __shared__ float Bs[TILE][36];
    __shared__ float f0tab[TAB_N];
    __shared__ float dtab[TAB_N];

    const int t = threadIdx.x;
    const int k = blockIdx.x;

    // fold mean zeroing into the first ceil(n/256) blocks
    {
        const int idx = k * 256 + t;
        if (idx < n) mean_out[idx] = 0.0f;
    }

    // closed-form upper-triangle decode (bi <= bj)
    const float nt = (float)ntiles;
    int bi = (int)(nt + 0.5f - sqrtf((nt + 0.5f) * (nt + 0.5f) - 2.0f * (float)k));
    while (bi > 0 && k < bi * ntiles - (bi * (bi - 1)) / 2) --bi;
    while (k >= (bi + 1) * ntiles - ((bi + 1) * bi) / 2) ++bi;
    const int bj = bi + (k - (bi * ntiles - (bi * (bi - 1)) / 2));

    const float alpha = alpha_p[0];
    const float oscale = os_p[0];
    const float nalpha = -alpha;
    const float rs2a = rsqrtf(2.0f * alpha);

    // Build pow table: f(t) = t^(-alpha) at bucket boundaries. 3 entries/thread.
#pragma unroll
    for (int e = t; e < TAB_N; e += 256) {
        const float t0 = __int_as_float((TAB_BASE + e) << 17);
        const float t1 = __int_as_float((TAB_BASE + e + 1) << 17);
        const float g0 = EXP2F(nalpha * LOG2F(t0));
        const float g1 = EXP2F(nalpha * LOG2F(t1));
        f0tab[e] = g0;
        dtab[e] = (g1 - g0) * 0x1p-17f;
    }

    // Stage tiles pre-scaled by 1/(l_d * sqrt(2a)).
    {
        const int row = t >> 3;
        const int q = (t & 7) * 4;
        const float4 lv = *reinterpret_cast<const float4*>(&ls[q]);
        const float4 a = *reinterpret_cast<const float4*>(&x[(size_t)(bi * TILE + row) * D + q]);
        const float4 b = *reinterpret_cast<const float4*>(&x[(size_t)(bj * TILE + row) * D + q]);
        const float w0 = rs2a / lv.x, w1 = rs2a / lv.y, w2 = rs2a / lv.z, w3 = rs2a / lv.w;
        As[row][q + 0] = a.x * w0;  Bs[row][q + 0] = b.x * w0;
        As[row][q + 1] = a.y * w1;  Bs[row][q + 1] = b.y * w1;
        As[row][q + 2] = a.z * w2;  Bs[row][q + 2] = b.z * w2;
        As[row][q + 3] = a.w * w3;  Bs[row][q + 3] = b.w * w3;
    }
    __syncthreads();

    const int c = t & 31;
    const int r0 = t >> 5;

    float bs[D];
#pragma unroll
    for (int q = 0; q < D; q += 4) {
        const float4 v = *reinterpret_cast<const float4*>(&Bs[c][q]);
        bs[q] = v.x; bs[q + 1] = v.y; bs[q + 2] = v.z; bs[q + 3] = v.w;
    }

    float acc[4];
#pragma unroll
    for (int kk = 0; kk < 4; ++kk) {
        const int r = r0 + kk * 8;
        float as[D];
#pragma unroll
        for (int q = 0; q < D; q += 4) {
            const float4 v = *reinterpret_cast<const float4*>(&As[r][q]);
            as[q] = v.x; as[q + 1] = v.y; as[q + 2] = v.z; as[q + 3] = v.w;
        }
        float s0 = 0.0f, s1 = 0.0f;
#pragma unroll
        for (int d = 0; d < D; d += 2) {
            {
                const float diff = as[d] - bs[d];
                float tv = fmaf(diff, diff, 1.0f);
                tv = fminf(tv, 4095.0f);
                const int bits = __float_as_int(tv);
                const int idx = (bits >> 17) - TAB_BASE;
                const float frac = (float)(bits & 0x1FFFF);
                s0 += fmaf(frac, dtab[idx], f0tab[idx]);
            }
            {
                const float diff = as[d + 1] - bs[d + 1];
                float tv = fmaf(diff, diff, 1.0f);
                tv = fminf(tv, 4095.0f);
                const int bits = __float_as_int(tv);
                const int idx = (bits >> 17) - TAB_BASE;
                const float frac = (float)(bits & 0x1FFFF);
                s1 += fmaf(frac, dtab[idx], f0tab[idx]);
            }
        }
        acc[kk] = oscale * (s0 + s1);
    }

    // direct (coalesced) write of own tile
#pragma unroll
    for (int kk = 0; kk < 4; ++kk) {
        const int r = r0 + kk * 8;
        covar[(size_t)(bi * TILE + r) * n + (bj * TILE + c)] = acc[kk];
    }

    // mirror write for off-diagonal tiles: transpose through LDS
    if (bi != bj) {
        __syncthreads();
#pragma unroll
        for (int kk = 0; kk < 4; ++kk) {
            As[r0 + kk * 8][c] = acc[kk];
        }
        __syncthreads();
#pragma unroll
        for (int kk = 0; kk < 4; ++kk) {
            const int rr = r0 + kk * 8;
            const float v = As[c][rr];
            covar[(size_t)(bj * TILE + rr) * n + (bi * TILE + c)] = v;
        }
    }
}

extern "C" void kernel_launch(void* const* d_in, const int* in_sizes, int n_in,
                              void* d_out, int out_size, void* d_ws, size_t ws_size,
                              hipStream_t stream) {
    const float* x = (const float*)d_in[0];
    const float* ls = (const float*)d_in[1];
    const float* alpha_p = (const float*)d_in[2];
    const float* os_p = (const float*)d_in[3];

    const int n = in_sizes[0] / D;       // 2048
    const int ntiles = n / TILE;         // 64
    const int nblocks = ntiles * (ntiles + 1) / 2;  // 2080

    float* mean_out = (float*)d_out;
    float* covar = (float*)d_out + n;

    rq_covar_sym_kernel<<<nblocks, 256, 0, stream>>>(x, ls, alpha_p, os_p,
                                                     mean_out, covar, n, ntiles);
}

// Round 5
// 85.617 us; speedup vs baseline: 1.0209x; 1.0209x over previous
//
#include <hip/hip_runtime.h>

// Additive RQ kernel, symmetric: covar[i,j] = os * sum_d (1 + ((x_i,d-x_j,d)/l_d)^2/(2a))^(-a)
// Output layout: [ mean (N floats, zeros) | covar (N*N floats) ]
// Upper-triangle 32x32 tiles; mirror via LDS transpose.
//
// pow() via SINGLE-GATHER bf16-packed piecewise-linear LDS table over bits of t=1+z:
//   idx  = (bits>>17) - 8128   (exponent + 6 mantissa bits; t in [1,4096))
//   word = tab[idx]  ->  f0 = bf16(hi16), slope = bf16(lo16), slope pre-scaled by 2^-17
//   term = fma(float(bits & 0x1FFFF), slope, f0)
// Error: interp <= 1.8e-4 + bf16 quant <= 1e-3 per term; x32 terms ~ 0.04 << 0.577.
// Table duplicated (even/odd lanes, stride 776 words -> +8 bank shift) to cut
// gather conflicts; per-lane base folds into address math (no inner-loop cost).

#define D 32
#define TILE 32
#define TAB_N 768           // 12 octaves x 64 buckets: t in [1, 4096)
#define TAB_BASE 8128       // 0x3f800000 >> 17
#define TAB_STRIDE 776      // copy stride in words: 776 % 32 = 8 -> bank shift
#define TMAX_BITS 0x457FFFFFu  // just under 4096.0f

#if __has_builtin(__builtin_amdgcn_exp2f)
#define EXP2F(x) __builtin_amdgcn_exp2f(x)
#else
#define EXP2F(x) exp2f(x)
#endif
#if __has_builtin(__builtin_amdgcn_logf)
#define LOG2F(x) __builtin_amdgcn_logf(x)
#else
#define LOG2F(x) __log2f(x)
#endif

__device__ __forceinline__ unsigned bf16_rne(float f) {
    unsigned u = __float_as_uint(f);
    return (u + 0x7FFFu + ((u >> 16) & 1u)) >> 16;  // round-to-nearest-even
}

__global__ __launch_bounds__(256) void rq_covar_sym_kernel(
    const float* __restrict__ x,
    const float* __restrict__ ls,
    const float* __restrict__ alpha_p,
    const float* __restrict__ os_p,
    float* __restrict__ mean_out,
    float* __restrict__ covar,
    int n, int ntiles)
{
    __shared__ float As[TILE][36];
    __shared__ float Bs[TILE][36];
    __shared__ int tab[2 * TAB_STRIDE];

    const int t = threadIdx.x;
    const int k = blockIdx.x;

    // fold mean zeroing into the first ceil(n/256) blocks
    {
        const int idx = k * 256 + t;
        if (idx < n) mean_out[idx] = 0.0f;
    }

    // closed-form upper-triangle decode (bi <= bj)
    const float nt = (float)ntiles;
    int bi = (int)(nt + 0.5f - sqrtf((nt + 0.5f) * (nt + 0.5f) - 2.0f * (float)k));
    while (bi > 0 && k < bi * ntiles - (bi * (bi - 1)) / 2) --bi;
    while (k >= (bi + 1) * ntiles - ((bi + 1) * bi) / 2) ++bi;
    const int bj = bi + (k - (bi * ntiles - (bi * (bi - 1)) / 2));

    const float alpha = alpha_p[0];
    const float oscale = os_p[0];
    const float nalpha = -alpha;
    const float rs2a = rsqrtf(2.0f * alpha);

    // Build packed table: 3 entries/thread, written to both copies.
#pragma unroll
    for (int e = t; e < TAB_N; e += 256) {
        const float t0 = __int_as_float((TAB_BASE + e) << 17);
        const float t1 = __int_as_float((TAB_BASE + e + 1) << 17);
        const float g0 = EXP2F(nalpha * LOG2F(t0));
        const float g1 = EXP2F(nalpha * LOG2F(t1));
        const unsigned hi = bf16_rne(g0);
        const unsigned lo = bf16_rne((g1 - g0) * 0x1p-17f);
        const int w = (int)((hi << 16) | lo);
        tab[e] = w;
        tab[TAB_STRIDE + e] = w;
    }

    // Stage tiles pre-scaled by 1/(l_d * sqrt(2a)).
    {
        const int row = t >> 3;
        const int q = (t & 7) * 4;
        const float4 lv = *reinterpret_cast<const float4*>(&ls[q]);
        const float4 a = *reinterpret_cast<const float4*>(&x[(size_t)(bi * TILE + row) * D + q]);
        const float4 b = *reinterpret_cast<const float4*>(&x[(size_t)(bj * TILE + row) * D + q]);
        const float w0 = rs2a / lv.x, w1 = rs2a / lv.y, w2 = rs2a / lv.z, w3 = rs2a / lv.w;
        As[row][q + 0] = a.x * w0;  Bs[row][q + 0] = b.x * w0;
        As[row][q + 1] = a.y * w1;  Bs[row][q + 1] = b.y * w1;
        As[row][q + 2] = a.z * w2;  Bs[row][q + 2] = b.z * w2;
        As[row][q + 3] = a.w * w3;  Bs[row][q + 3] = b.w * w3;
    }
    __syncthreads();

    const int c = t & 31;
    const int r0 = t >> 5;
    const int* __restrict__ myTab = tab + (t & 1) * TAB_STRIDE;  // per-lane copy

    float bs[D];
#pragma unroll
    for (int q = 0; q < D; q += 4) {
        const float4 v = *reinterpret_cast<const float4*>(&Bs[c][q]);
        bs[q] = v.x; bs[q + 1] = v.y; bs[q + 2] = v.z; bs[q + 3] = v.w;
    }

    float acc[4];
#pragma unroll
    for (int kk = 0; kk < 4; ++kk) {
        const int r = r0 + kk * 8;
        float as[D];
#pragma unroll
        for (int q = 0; q < D; q += 4) {
            const float4 v = *reinterpret_cast<const float4*>(&As[r][q]);
            as[q] = v.x; as[q + 1] = v.y; as[q + 2] = v.z; as[q + 3] = v.w;
        }
        float s0 = 0.0f, s1 = 0.0f, s2 = 0.0f, s3 = 0.0f;
#pragma unroll
        for (int d = 0; d < D; d += 4) {
#pragma unroll
            for (int j = 0; j < 4; ++j) {
                const float diff = as[d + j] - bs[d + j];
                const float tv = fmaf(diff, diff, 1.0f);
                unsigned ib = __float_as_uint(tv);
                ib = min(ib, TMAX_BITS);
                const int idx = (int)(ib >> 17) - TAB_BASE;
                const int w = myTab[idx];
                const float frac = (float)(ib & 0x1FFFFu);
                const float f0 = __int_as_float((unsigned)w & 0xFFFF0000u);
                const float sl = __int_as_float((unsigned)w << 16);
                const float term = fmaf(frac, sl, f0);
                if (j == 0) s0 += term;
                else if (j == 1) s1 += term;
                else if (j == 2) s2 += term;
                else s3 += term;
            }
        }
        acc[kk] = oscale * ((s0 + s1) + (s2 + s3));
    }

    // direct (coalesced) write of own tile
#pragma unroll
    for (int kk = 0; kk < 4; ++kk) {
        const int r = r0 + kk * 8;
        covar[(size_t)(bi * TILE + r) * n + (bj * TILE + c)] = acc[kk];
    }

    // mirror write for off-diagonal tiles: transpose through LDS
    if (bi != bj) {
        __syncthreads();
#pragma unroll
        for (int kk = 0; kk < 4; ++kk) {
            As[r0 + kk * 8][c] = acc[kk];
        }
        __syncthreads();
#pragma unroll
        for (int kk = 0; kk < 4; ++kk) {
            const int rr = r0 + kk * 8;
            const float v = As[c][rr];
            covar[(size_t)(bj * TILE + rr) * n + (bi * TILE + c)] = v;
        }
    }
}

extern "C" void kernel_launch(void* const* d_in, const int* in_sizes, int n_in,
                              void* d_out, int out_size, void* d_ws, size_t ws_size,
                              hipStream_t stream) {
    const float* x = (const float*)d_in[0];
    const float* ls = (const float*)d_in[1];
    const float* alpha_p = (const float*)d_in[2];
    const float* os_p = (const float*)d_in[3];

    const int n = in_sizes[0] / D;       // 2048
    const int ntiles = n / TILE;         // 64
    const int nblocks = ntiles * (ntiles + 1) / 2;  // 2080

    float* mean_out = (float*)d_out;
    float* covar = (float*)d_out + n;

    rq_covar_sym_kernel<<<nblocks, 256, 0, stream>>>(x, ls, alpha_p, os_p,
                                                     mean_out, covar, n, ntiles);
}